// Round 7
// baseline (246.780 us; speedup 1.0000x reference)
//
#include <hip/hip_runtime.h>
#include <cstdint>
#include <cstddef>
#include <utility>

#define SS 512
#define TT 32
#define NB 256
#define KSTEPS 510  // SS-2

// ---------- unroll helper (compile-time indices -> registers) ----------
template <typename F, size_t... Is>
__device__ __forceinline__ void unroll_impl(F&& f, std::index_sequence<Is...>) {
  (f(std::integral_constant<int, (int)Is>{}), ...);
}
template <int N, typename F>
__device__ __forceinline__ void unrollN(F&& f) {
  unroll_impl(f, std::make_index_sequence<N>{});
}

// butterfly xor D within each 32-lane group (one-time reductions only)
template <int D>
__device__ __forceinline__ float bfly32(float v) {
  return __int_as_float(__builtin_amdgcn_ds_swizzle(__float_as_int(v), (D << 10) | 0x1f));
}
template <int D>
__device__ __forceinline__ int bfly32i(int v) {
  return __builtin_amdgcn_ds_swizzle(v, (D << 10) | 0x1f);
}

__device__ __forceinline__ float max3f(float a, float b, float c) {
  return fmaxf(fmaxf(a, b), c);  // fuses to v_max3_f32
}

// ---------- mask dtype autodetect (bool may arrive as i32 / u8 / f32) ----------
__device__ __forceinline__ int mask_mode(const void* m) {
  int w0 = ((const int*)m)[0];          // element (0,0) is always true (L>=256)
  if (w0 == 1) return 0;                // int32 0/1
  if (w0 == 0x3f800000) return 2;       // float32 1.0
  return 1;                             // uint8
}
__device__ __forceinline__ bool mask_at(const void* m, int idx, int mode) {
  if (mode == 0) return ((const int*)m)[idx] != 0;
  if (mode == 2) return ((const float*)m)[idx] != 0.0f;
  return ((const unsigned char*)m)[idx] != 0;
}

__device__ __forceinline__ int seq_length(const void* mask, int b, int tid, int mode) {
  int cnt = 0;
  for (int s = tid; s < SS; s += 64) cnt += mask_at(mask, b * SS + s, mode) ? 1 : 0;
  for (int d = 1; d < 64; d <<= 1) cnt += __shfl_xor(cnt, d, 64);
  return cnt;
}

// ---------- K1: fused forward / viterbi / gold (role by blockIdx) ----------
// Lane l owns tag j = l&31; lanes l and l+32 do IDENTICAL full-width work
// (32-source reduction each) -> zero cross-lane ops in the recurrence chain.
// Transport: 32-float LDS array; per step 1 ds_write_b32 (2-way same-addr,
// free) + 8 uniform-address ds_read_b128 broadcasts (one latency, pipelined).
__global__ __launch_bounds__(64) void crf_main_kernel(
    const float* __restrict__ feats, const float* __restrict__ trans,
    const void* __restrict__ mask, const int* __restrict__ tags,
    unsigned char* __restrict__ ws_bp, float* __restrict__ ws_fwd,
    float* __restrict__ ws_gold, int* __restrict__ ws_ptr) {
  const int blk = blockIdx.x;
  const int tid = threadIdx.x;
  const int mode = mask_mode(mask);
  const int j = tid & 31;   // owned tag

  __shared__ __align__(16) float qlds[TT];

  if (blk < NB) {
    // ========== FORWARD, exp-space: q' = exp(f) * (E^T q), exact 2^k rescale ==========
    const int b = blk;
    const int L = seq_length(mask, b, tid, mode);
    const int steps = L - 2;
    const float* fb = feats + (size_t)b * (SS * TT);

    float E[TT];  // full column j of exp(trans)
    unrollN<TT>([&](auto I) { constexpr int ii = I; E[ii] = __expf(trans[ii * TT + j]); });

    float q = __expf(fb[TT + j]);
    int Eacc = 0;
    qlds[j] = q;
    asm volatile("" ::: "memory");
    const float4* qv = (const float4*)qlds;

    float fA = fb[2 * TT + j], fB = fb[3 * TT + j], fC = fb[4 * TT + j];
    float ef = __expf(fA);   // exp for the CURRENT step (precomputed off-path)

    auto step = [&](int k, bool resc) {
      // issue the dependent LDS reads first
      float4 Q0 = qv[0], Q1 = qv[1], Q2 = qv[2], Q3 = qv[3];
      float4 Q4 = qv[4], Q5 = qv[5], Q6 = qv[6], Q7 = qv[7];
      // off-path work while reads are in flight
      int r5 = k + 5; r5 = (r5 < SS) ? r5 : (SS - 1);
      float fD = fb[r5 * TT + j];                 // global prefetch depth-3
      float efN = __expf(fB);                     // next step's exp
      // on-path: 32-fma dot, 4 chains of depth 8
      float a0, a1, a2, a3;
      a0 = Q0.x * E[0];  a1 = Q0.y * E[1];  a2 = Q0.z * E[2];  a3 = Q0.w * E[3];
      a0 = fmaf(Q1.x, E[4], a0);  a1 = fmaf(Q1.y, E[5], a1);  a2 = fmaf(Q1.z, E[6], a2);  a3 = fmaf(Q1.w, E[7], a3);
      a0 = fmaf(Q2.x, E[8], a0);  a1 = fmaf(Q2.y, E[9], a1);  a2 = fmaf(Q2.z, E[10], a2); a3 = fmaf(Q2.w, E[11], a3);
      a0 = fmaf(Q3.x, E[12], a0); a1 = fmaf(Q3.y, E[13], a1); a2 = fmaf(Q3.z, E[14], a2); a3 = fmaf(Q3.w, E[15], a3);
      a0 = fmaf(Q4.x, E[16], a0); a1 = fmaf(Q4.y, E[17], a1); a2 = fmaf(Q4.z, E[18], a2); a3 = fmaf(Q4.w, E[19], a3);
      a0 = fmaf(Q5.x, E[20], a0); a1 = fmaf(Q5.y, E[21], a1); a2 = fmaf(Q5.z, E[22], a2); a3 = fmaf(Q5.w, E[23], a3);
      a0 = fmaf(Q6.x, E[24], a0); a1 = fmaf(Q6.y, E[25], a1); a2 = fmaf(Q6.z, E[26], a2); a3 = fmaf(Q6.w, E[27], a3);
      a0 = fmaf(Q7.x, E[28], a0); a1 = fmaf(Q7.y, E[29], a1); a2 = fmaf(Q7.z, E[30], a2); a3 = fmaf(Q7.w, E[31], a3);
      float P = (a0 + a1) + (a2 + a3);
      q = ef * P;
      if (resc) {
        int qb = __builtin_amdgcn_readfirstlane(__float_as_int(q));
        int e = (qb >> 23) & 0xff;
        Eacc += e - 127;
        q *= __int_as_float((254 - e) << 23);     // exact power-of-two scale
      }
      qlds[j] = q;
      asm volatile("" ::: "memory");
      fA = fB; fB = fC; fC = fD; ef = efN;
    };

    int k = 0;
    for (; k + 4 <= steps; k += 4) {
      step(k, false); step(k + 1, false); step(k + 2, false); step(k + 3, true);
    }
    for (; k < steps; ++k) step(k, false);

    // forward score = log(sum_j q_j) + Eacc*ln2
    float s = q;
    unrollN<5>([&](auto D) { constexpr int d = 1 << D; s += bfly32<d>(s); });
    if (tid == 0) ws_fwd[b] = __logf(s) + (float)Eacc * 0.69314718056f;

  } else if (blk < 2 * NB) {
    // ================= VITERBI (bit-exact vs reference) =================
    const int b = blk - NB;
    const int L = seq_length(mask, b, tid, mode);
    const int steps = L - 2;
    const float* fb = feats + (size_t)b * (SS * TT);
    unsigned char* bpb = ws_bp + (size_t)b * (KSTEPS * TT);

    float C[TT];  // full column j of trans
    unrollN<TT>([&](auto I) { constexpr int ii = I; C[ii] = trans[ii * TT + j]; });

    float p = fb[TT + j];
    qlds[j] = p;
    asm volatile("" ::: "memory");
    const float4* qv = (const float4*)qlds;

    float fA = fb[2 * TT + j], fB = fb[3 * TT + j], fC = fb[4 * TT + j];
    float dd[TT];  // fl(f_j + tr_ij) for the CURRENT step (precomputed off-path)
    unrollN<TT>([&](auto I) { constexpr int ii = I; dd[ii] = fA + C[ii]; });

    auto step = [&](int k) {
      // dependent LDS reads first
      float4 Q0 = qv[0], Q1 = qv[1], Q2 = qv[2], Q3 = qv[3];
      float4 Q4 = qv[4], Q5 = qv[5], Q6 = qv[6], Q7 = qv[7];
      // off-path while reads fly: prefetch + next step's dd
      int r5 = k + 5; r5 = (r5 < SS) ? r5 : (SS - 1);
      float fD = fb[r5 * TT + j];
      float nd[TT];
      unrollN<TT>([&](auto I) { constexpr int ii = I; nd[ii] = fB + C[ii]; });
      // on-path: cur = p_i + dd_i (reference order fl(fl(f+tr)+p)), exact max tree
      float cur[TT];
      cur[0] = Q0.x + dd[0];   cur[1] = Q0.y + dd[1];   cur[2] = Q0.z + dd[2];   cur[3] = Q0.w + dd[3];
      cur[4] = Q1.x + dd[4];   cur[5] = Q1.y + dd[5];   cur[6] = Q1.z + dd[6];   cur[7] = Q1.w + dd[7];
      cur[8] = Q2.x + dd[8];   cur[9] = Q2.y + dd[9];   cur[10] = Q2.z + dd[10]; cur[11] = Q2.w + dd[11];
      cur[12] = Q3.x + dd[12]; cur[13] = Q3.y + dd[13]; cur[14] = Q3.z + dd[14]; cur[15] = Q3.w + dd[15];
      cur[16] = Q4.x + dd[16]; cur[17] = Q4.y + dd[17]; cur[18] = Q4.z + dd[18]; cur[19] = Q4.w + dd[19];
      cur[20] = Q5.x + dd[20]; cur[21] = Q5.y + dd[21]; cur[22] = Q5.z + dd[22]; cur[23] = Q5.w + dd[23];
      cur[24] = Q6.x + dd[24]; cur[25] = Q6.y + dd[25]; cur[26] = Q6.z + dd[26]; cur[27] = Q6.w + dd[27];
      cur[28] = Q7.x + dd[28]; cur[29] = Q7.y + dd[29]; cur[30] = Q7.z + dd[30]; cur[31] = Q7.w + dd[31];
      float t0 = max3f(cur[0], cur[1], cur[2]);
      float t1 = max3f(cur[3], cur[4], cur[5]);
      float t2 = max3f(cur[6], cur[7], cur[8]);
      float t3 = max3f(cur[9], cur[10], cur[11]);
      float t4 = max3f(cur[12], cur[13], cur[14]);
      float t5 = max3f(cur[15], cur[16], cur[17]);
      float t6 = max3f(cur[18], cur[19], cur[20]);
      float t7 = max3f(cur[21], cur[22], cur[23]);
      float t8 = max3f(cur[24], cur[25], cur[26]);
      float t9 = max3f(cur[27], cur[28], cur[29]);
      float ta = fmaxf(cur[30], cur[31]);
      float u0 = max3f(t0, t1, t2);
      float u1 = max3f(t3, t4, t5);
      float u2 = max3f(t6, t7, t8);
      float u3 = fmaxf(t9, ta);
      float vmax = fmaxf(fmaxf(u0, u1), fmaxf(u2, u3));
      p = vmax;
      qlds[j] = vmax;                   // write ASAP (next read depends on it)
      asm volatile("" ::: "memory");
      // off-path: first-max index (descending overwrite-on-equal = jnp.argmax)
      int bi = 31;
      unrollN<TT>([&](auto I) { constexpr int ii = 31 - I; bi = (cur[ii] == vmax) ? ii : bi; });
      if (tid < 32) bpb[k * TT + j] = (unsigned char)bi;
      unrollN<TT>([&](auto I) { constexpr int ii = I; dd[ii] = nd[ii]; });
      fA = fB; fB = fC; fC = fD;
    };

    int k = 0;
    for (; k + 4 <= steps; k += 4) { step(k); step(k + 1); step(k + 2); step(k + 3); }
    for (; k < steps; ++k) step(k);

    // pointer = first-max argmax over tags of p
    float v = p;
    int idx = j;
    unrollN<5>([&](auto D) {
      constexpr int d = 1 << D;
      float vo = bfly32<d>(v);
      int io = bfly32i<d>(idx);
      bool take = (vo > v) || ((vo == v) && (io < idx));
      v = take ? vo : v;
      idx = take ? io : idx;
    });
    if (tid == 0) ws_ptr[b] = idx;
    // zero bp rows k in [steps, 510): reference masks bps to 0 there
    int* bpw = (int*)bpb;
    for (int w = steps * 8 + tid; w < KSTEPS * 8; w += 64) bpw[w] = 0;

  } else {
    // ================= GOLD SCORE =================
    const int b = blk - 2 * NB;
    float acc = 0.0f;
    for (int s = tid; s < SS; s += 64) {
      if (s == 0) continue;
      if (!mask_at(mask, b * SS + s, mode)) continue;
      int tg = tags[b * SS + s];
      if (tg == -100) tg = 0;
      float e = feats[((size_t)b * SS + s) * TT + tg];
      if (s >= 2) {
        int tp = tags[b * SS + s - 1];
        if (tp == -100) tp = 0;
        e += trans[tp * TT + tg];
      }
      acc += e;
    }
    for (int d = 1; d < 64; d <<= 1) acc += __shfl_xor(acc, d, 64);
    if (tid == 0) ws_gold[b] = acc;
  }
}

// ---------- K2: chunk-parallel backtrace + loss/path_score finish ----------
__global__ __launch_bounds__(512) void crf_backtrace_kernel(
    const unsigned char* __restrict__ ws_bp, const int* __restrict__ ws_ptr,
    const float* __restrict__ ws_fwd, const float* __restrict__ ws_gold,
    float* __restrict__ out) {
  __shared__ unsigned char bp[KSTEPS * TT];     // 16320 B
  __shared__ unsigned char path[KSTEPS * TT];   // 16320 B
  __shared__ int entries[8];

  const int b = blockIdx.x;
  const int tid = threadIdx.x;
  float* out_decode = out + 1 + NB;

  if (tid == 0) out[1 + b] = 0.0f;  // path_score = zeros(B)
  if (b == 0 && tid >= 64 && tid < 128) {
    int t = tid - 64;
    float sf = 0.0f, sg = 0.0f;
    for (int r = 0; r < 4; ++r) { sf += ws_fwd[t + 64 * r]; sg += ws_gold[t + 64 * r]; }
    for (int d = 1; d < 64; d <<= 1) { sf += __shfl_xor(sf, d, 64); sg += __shfl_xor(sg, d, 64); }
    if (t == 0) out[0] = (sf - sg) / 256.0f;
  }

  // stage bp to LDS
  const int* src = (const int*)(ws_bp + (size_t)b * (KSTEPS * TT));
  int* dst = (int*)bp;
  for (int w = tid; w < KSTEPS * 8; w += 512) dst[w] = src[w];
  __syncthreads();

  // each wave = one 64-step chunk; lanes 0..31 = entry-tag hypotheses
  const int wave = tid >> 6;
  const int lane = tid & 63;
  if (lane < 32) {
    const int lo = wave * 64;
    const int hi = (lo + 64 < KSTEPS) ? (lo + 64) : KSTEPS;
    int ptr = lane;
    for (int k = hi - 1; k >= lo; --k) {
      ptr = bp[k * TT + ptr];
      path[k * TT + lane] = (unsigned char)ptr;
    }
  }
  __syncthreads();

  // compose chunk entries from the top (chunk 7 enters with pointer)
  if (tid == 0) {
    int e = ws_ptr[b];
    for (int c = 7; c >= 0; --c) {
      entries[c] = e;
      e = path[(c * 64) * TT + e];
    }
  }
  __syncthreads();

  // decode row: [0, ptrs[0..509], pointer]
  const int s = tid;
  int val;
  if (s == 0) val = 0;
  else if (s <= KSTEPS) { int k = s - 1; val = path[k * TT + entries[k >> 6]]; }
  else val = ws_ptr[b];
  out_decode[(size_t)b * SS + s] = (float)val;
}

extern "C" void kernel_launch(void* const* d_in, const int* in_sizes, int n_in,
                              void* d_out, int out_size, void* d_ws, size_t ws_size,
                              hipStream_t stream) {
  const float* feats = (const float*)d_in[0];
  const float* trans = (const float*)d_in[1];
  const void* mask = d_in[2];
  const int* tags = (const int*)d_in[3];
  float* out = (float*)d_out;

  unsigned char* ws = (unsigned char*)d_ws;
  const size_t BP_BYTES = (size_t)NB * KSTEPS * TT;  // 4,177,920
  unsigned char* ws_bp = ws;
  float* ws_fwd = (float*)(ws + BP_BYTES);
  float* ws_gold = (float*)(ws + BP_BYTES + 1024);
  int* ws_ptr = (int*)(ws + BP_BYTES + 2048);

  hipLaunchKernelGGL(crf_main_kernel, dim3(3 * NB), dim3(64), 0, stream,
                     feats, trans, mask, tags, ws_bp, ws_fwd, ws_gold, ws_ptr);
  hipLaunchKernelGGL(crf_backtrace_kernel, dim3(NB), dim3(512), 0, stream,
                     ws_bp, ws_ptr, ws_fwd, ws_gold, out);
}